// Round 1
// baseline (830.304 us; speedup 1.0000x reference)
//
#include <hip/hip_runtime.h>
#include <hip/hip_bf16.h>

// B=4, T=256, U=128, H=512, P=512, HID=512, V=1024
// inputs: f(4,256,512) g(4,128,512) W1(1024,512) b1(512) W2(512,1024) b2(1024)
// out: (4,256,128,1024) fp32

typedef __attribute__((ext_vector_type(8)))  short          short8;
typedef __attribute__((ext_vector_type(8)))  unsigned short ushort8;
typedef __attribute__((ext_vector_type(4)))  float          f32x4;
typedef __attribute__((ext_vector_type(16))) float          f32x16;

__device__ __forceinline__ unsigned short f2bf(float x) {
    unsigned u = __builtin_bit_cast(unsigned, x);
    u += 0x7FFFu + ((u >> 16) & 1u);          // RNE
    return (unsigned short)(u >> 16);
}
__device__ __forceinline__ float bf2f(unsigned short s) {
    return __builtin_bit_cast(float, (unsigned)s << 16);
}

// ---------------------------------------------------------------------------
// Kernel 1: prepack W2 (512x1024 fp32) into bf16 fragment-direct layout.
// Frag (nfg in [0,32), kc in [0,32)): lane l holds W2[kc*16+(l>>5)*8+j][nfg*32+(l&31)]
// dst short index = ((nfg*32+kc)*64 + l)*8 + j  == t*8+j with t = global thread id
// ---------------------------------------------------------------------------
__global__ __launch_bounds__(256) void prep_w2(const float* __restrict__ W2,
                                               unsigned short* __restrict__ W2pk) {
    int t   = blockIdx.x * 256 + threadIdx.x;   // 65536 threads
    int l   = t & 63;
    int kc  = (t >> 6) & 31;
    int nfg = t >> 11;
    int n   = nfg * 32 + (l & 31);
    int kb  = kc * 16 + (l >> 5) * 8;
    ushort8 v;
#pragma unroll
    for (int j = 0; j < 8; ++j) v[j] = f2bf(W2[(kb + j) * 1024 + n]);
    *(ushort8*)&W2pk[(size_t)t * 8] = v;
}

// ---------------------------------------------------------------------------
// Kernel 2: projections.
//  blocks [0,128):  hf[m,d] = sum_k f[m,k]*W1[k,d] + b1[d]   (fp32, 1024x512)
//  blocks [128,192): hg[m,d] = sum_k g[m,k]*W1[512+k,d]      (bf16, 512x512)
// 64x64 tile per block, 4 waves (2x2), wave tile 32x32, mfma 16x16x32 bf16.
// ---------------------------------------------------------------------------
__global__ __launch_bounds__(256) void proj(const float* __restrict__ f,
                                            const float* __restrict__ g,
                                            const float* __restrict__ W1,
                                            const float* __restrict__ b1,
                                            float* __restrict__ hf,
                                            unsigned short* __restrict__ hg) {
    const int bx   = blockIdx.x;
    const bool isf = bx < 128;
    const float* A  = isf ? f : g;
    const int w1r0  = isf ? 0 : 512;
    const int lbx   = isf ? bx : bx - 128;
    const int nt    = lbx & 7, mt = lbx >> 3;
    const int m0    = mt * 64, n0 = nt * 64;

    __shared__ short As[64 * 40];   // [row][k] stride 40 elems (80B, 16B aligned)
    __shared__ short Bs[64 * 40];   // [n][k]

    const int tid = threadIdx.x, lane = tid & 63, wave = tid >> 6;
    const int wm = wave & 1, wn = wave >> 1;

    f32x4 acc[2][2] = {};

    for (int k0 = 0; k0 < 512; k0 += 32) {
        // stage A (64 rows x 32 k), fp32 -> bf16
        {
            int row = tid & 63, kq = tid >> 6;
            const float* src = A + (size_t)(m0 + row) * 512 + k0 + kq * 8;
            f32x4 v0 = *(const f32x4*)src;
            f32x4 v1 = *(const f32x4*)(src + 4);
            short8 p;
#pragma unroll
            for (int j = 0; j < 4; ++j) p[j]     = (short)f2bf(v0[j]);
#pragma unroll
            for (int j = 0; j < 4; ++j) p[4 + j] = (short)f2bf(v1[j]);
            *(short8*)&As[row * 40 + kq * 8] = p;
        }
        // stage B transposed: Bs[n][k] = W1[w1r0+k0+k][n0+n]
        {
            int n = tid & 63, kq = tid >> 6;
#pragma unroll
            for (int i = 0; i < 8; ++i) {
                int k = kq * 8 + i;
                Bs[n * 40 + k] = (short)f2bf(W1[(size_t)(w1r0 + k0 + k) * 512 + n0 + n]);
            }
        }
        __syncthreads();
        {
            const int q16 = (lane >> 4) * 8, l16 = lane & 15;
            short8 a0 = *(const short8*)&As[(wm * 32 +      l16) * 40 + q16];
            short8 a1 = *(const short8*)&As[(wm * 32 + 16 + l16) * 40 + q16];
            short8 b0 = *(const short8*)&Bs[(wn * 32 +      l16) * 40 + q16];
            short8 b1f= *(const short8*)&Bs[(wn * 32 + 16 + l16) * 40 + q16];
            acc[0][0] = __builtin_amdgcn_mfma_f32_16x16x32_bf16(a0, b0,  acc[0][0], 0, 0, 0);
            acc[0][1] = __builtin_amdgcn_mfma_f32_16x16x32_bf16(a0, b1f, acc[0][1], 0, 0, 0);
            acc[1][0] = __builtin_amdgcn_mfma_f32_16x16x32_bf16(a1, b0,  acc[1][0], 0, 0, 0);
            acc[1][1] = __builtin_amdgcn_mfma_f32_16x16x32_bf16(a1, b1f, acc[1][1], 0, 0, 0);
        }
        __syncthreads();
    }

    // epilogue: C/D 16x16: col=lane&15, row=(lane>>4)*4+reg
#pragma unroll
    for (int nf = 0; nf < 2; ++nf) {
        int col = n0 + wn * 32 + nf * 16 + (lane & 15);
        float bv = isf ? b1[col] : 0.0f;
#pragma unroll
        for (int mf = 0; mf < 2; ++mf) {
#pragma unroll
            for (int r = 0; r < 4; ++r) {
                int row = m0 + wm * 32 + mf * 16 + (lane >> 4) * 4 + r;
                float v = acc[mf][nf][r] + bv;
                if (isf) hf[(size_t)row * 512 + col] = v;
                else     hg[(size_t)row * 512 + col] = f2bf(v);
            }
        }
    }
}

// ---------------------------------------------------------------------------
// Kernel 3: joint. grid 4096: bx -> ntile = bx&3 (256 cols of V), mtile = bx>>2
// (one (b,t); rows = u in [0,128)). Tile 128x256, 4 waves (2m x 2n), wave tile
// 64x128, mfma 32x32x16 bf16. A built on the fly: fast_tanh(hf_row + hg).
// B frags loaded straight from prepacked global (no LDS).
// ---------------------------------------------------------------------------
__global__ __launch_bounds__(256, 2) void joint(const float* __restrict__ hf,
                                                const unsigned short* __restrict__ hg,
                                                const short8* __restrict__ W2pk,
                                                const float* __restrict__ b2,
                                                float* __restrict__ out) {
    const int bx    = blockIdx.x;
    const int nt    = bx & 3;
    const int mtile = bx >> 2;                      // = b*256 + t
    const float* hf_row = hf + (size_t)mtile * 512;
    const unsigned short* hg_b = hg + (size_t)(mtile >> 8) * 128 * 512;

    const int tid = threadIdx.x, lane = tid & 63, wave = tid >> 6;
    const int wm = wave & 1, wn = wave >> 1;

    __shared__ short As[128 * 72];                  // [u][k] stride 72 (144B)

    f32x16 acc[2][4] = {};

    const int kg = tid & 7, ubase = tid >> 3;       // kg: 8-elem k group, ubase 0..31

    for (int step = 0; step < 8; ++step) {
        const int k0 = step * 64;
        // ---- A construct: 128 u-rows x 64 k, bf16 into LDS ----
        float hfv[8];
        {
            const float* p = hf_row + k0 + kg * 8;
            *(f32x4*)&hfv[0] = *(const f32x4*)p;
            *(f32x4*)&hfv[4] = *(const f32x4*)(p + 4);
        }
#pragma unroll
        for (int r = 0; r < 4; ++r) {
            int u = ubase + 32 * r;
            ushort8 hv = *(const ushort8*)(hg_b + (size_t)u * 512 + k0 + kg * 8);
            short8 pck;
#pragma unroll
            for (int j = 0; j < 8; ++j) {
                float x = hfv[j] + bf2f(hv[j]);
                float tnh = x * __builtin_amdgcn_rcpf(1.0f + __builtin_fabsf(x));
                pck[j] = (short)f2bf(tnh);
            }
            *(short8*)&As[u * 72 + kg * 8] = pck;
        }
        __syncthreads();
        // ---- compute: 4 K-chunks of 16 ----
#pragma unroll
        for (int c = 0; c < 4; ++c) {
            const int kc = step * 4 + c;
            const int aoff = c * 16 + (lane >> 5) * 8;
            short8 a0 = *(const short8*)&As[(wm * 64 +      (lane & 31)) * 72 + aoff];
            short8 a1 = *(const short8*)&As[(wm * 64 + 32 + (lane & 31)) * 72 + aoff];
#pragma unroll
            for (int nf = 0; nf < 4; ++nf) {
                int nfg = nt * 8 + wn * 4 + nf;
                short8 bfrag = W2pk[(size_t)(nfg * 32 + kc) * 64 + lane];
                acc[0][nf] = __builtin_amdgcn_mfma_f32_32x32x16_bf16(a0, bfrag, acc[0][nf], 0, 0, 0);
                acc[1][nf] = __builtin_amdgcn_mfma_f32_32x32x16_bf16(a1, bfrag, acc[1][nf], 0, 0, 0);
            }
        }
        __syncthreads();
    }

    // ---- epilogue: C/D 32x32: col=lane&31, row=(reg&3)+8*(reg>>2)+4*(lane>>5) ----
    float* outb = out + (size_t)mtile * 128 * 1024 + nt * 256;
    const int cl = lane & 31, rq = (lane >> 5) * 4;
#pragma unroll
    for (int nf = 0; nf < 4; ++nf) {
        int col  = wn * 128 + nf * 32 + cl;
        float bv = b2[nt * 256 + col];
#pragma unroll
        for (int mf = 0; mf < 2; ++mf) {
#pragma unroll
            for (int reg = 0; reg < 16; ++reg) {
                int row = wm * 64 + mf * 32 + (reg & 3) + 8 * (reg >> 2) + rq;
                outb[(size_t)row * 1024 + col] = acc[mf][nf][reg] + bv;
            }
        }
    }
}

// ---------------------------------------------------------------------------
extern "C" void kernel_launch(void* const* d_in, const int* in_sizes, int n_in,
                              void* d_out, int out_size, void* d_ws, size_t ws_size,
                              hipStream_t stream) {
    const float* f  = (const float*)d_in[0];
    const float* g  = (const float*)d_in[1];
    const float* W1 = (const float*)d_in[2];
    const float* b1 = (const float*)d_in[3];
    const float* W2 = (const float*)d_in[4];
    const float* b2 = (const float*)d_in[5];
    float* out = (float*)d_out;

    char* ws = (char*)d_ws;
    unsigned short* W2pk = (unsigned short*)ws;                      // 1 MB
    float*          hf   = (float*)(ws + (1u << 20));                // 2 MB
    unsigned short* hg   = (unsigned short*)(ws + 3u * (1u << 20));  // 512 KB

    prep_w2<<<256, 256, 0, stream>>>(W2, W2pk);
    proj<<<192, 256, 0, stream>>>(f, g, W1, b1, hf, hg);
    joint<<<4096, 256, 0, stream>>>(hf, hg, (const short8*)W2pk, b2, out);
}